// Round 13
// baseline (194.310 us; speedup 1.0000x reference)
//
#include <hip/hip_runtime.h>

#define LQ 1024
#define DIM 128
#define NT 512
#define QT 32

typedef __attribute__((ext_vector_type(8))) short bf16x8;
typedef __attribute__((ext_vector_type(4))) float f32x4;
typedef __attribute__((ext_vector_type(2))) unsigned u32x2;

__device__ __forceinline__ unsigned pk2(float a, float b) {
  unsigned short ux = __builtin_bit_cast(unsigned short, (__bf16)a);
  unsigned short uy = __builtin_bit_cast(unsigned short, (__bf16)b);
  return (unsigned)ux | ((unsigned)uy << 16);
}
__device__ __forceinline__ bf16x8 pack8(f32x4 a, f32x4 b) {
  union { unsigned u[4]; bf16x8 v; } r;
  r.u[0] = pk2(a[0], a[1]); r.u[1] = pk2(a[2], a[3]);
  r.u[2] = pk2(b[0], b[1]); r.u[3] = pk2(b[2], b[3]);
  return r.v;
}

// ---------------- prepass: K fp32->bf16 copy; V fp32 -> bf16 transposed [d][k]
__global__ __launch_bounds__(NT)
void prep_kv(const float* __restrict__ Kp, const float* __restrict__ Vp,
             unsigned short* __restrict__ Kb, unsigned short* __restrict__ VT)
{
  __shared__ __align__(16) char lds[32768];
  const int t = (int)threadIdx.x;
  const int bid = (int)blockIdx.x;            // 256 blocks
  const int logical = (bid & 7) * 32 + (bid >> 3);  // XCD-chunked (matches main)
  const int b = logical >> 3;                 // batch
  const int o = logical & 7;                  // k-octant (128 rows)
  const size_t boff = (size_t)b * (LQ * DIM);

  { // K convert-copy rows [o*128, o*128+128)
    const float* src = Kp + boff + (size_t)o * 128 * DIM;
    unsigned short* dst = Kb + boff + (size_t)o * 128 * DIM;
    #pragma unroll
    for (int j = 0; j < 8; ++j) {
      int off = j * 2048 + t * 4;
      f32x4 v = __builtin_nontemporal_load((const f32x4*)(src + off));
      u32x2 p; p[0] = pk2(v[0], v[1]); p[1] = pk2(v[2], v[3]);
      *(u32x2*)(dst + off) = p;
    }
  }
  { // V transpose via swizzled LDS: rows [o*128..+128) -> VT[d][o*128+k]
    const float* src = Vp + boff + (size_t)o * 128 * DIM;
    #pragma unroll
    for (int i = 0; i < 8; ++i) {
      int kr = i * 16 + (t >> 5);
      int d4 = t & 31;
      f32x4 v = __builtin_nontemporal_load(
          (const f32x4*)(src + (size_t)kr * DIM + d4 * 4));
      #pragma unroll
      for (int dd = 0; dd < 4; ++dd) {
        int d = d4 * 4 + dd;
        int byt = (d * 256 + kr * 2) ^ ((d & 7) << 4);
        *(unsigned short*)(lds + byt) =
            __builtin_bit_cast(unsigned short, (__bf16)v[dd]);
      }
    }
    __syncthreads();
    #pragma unroll
    for (int j = 0; j < 4; ++j) {
      int d = j * 32 + (t >> 4);
      int k4 = t & 15;
      int byt = (d * 256 + k4 * 16) ^ ((d & 7) << 4);
      f32x4 x = *(const f32x4*)(lds + byt);
      *(f32x4*)(VT + boff + (size_t)d * LQ + o * 128 + k4 * 8) = x;
    }
  }
}

// ---------------- main kernel: EXACT R9 structure (verified passing, 88us).
// VAR: 0=full (writes Op). Ablation builds write wsout instead:
//   3 = phase 1 only; 2 = phases 1-2; 1 = phases 1-3. Each epilogue consumes
//   the phase outputs so nothing upstream is DCE'd (rule #17).
template<bool PRE, int VAR>
__global__ __launch_bounds__(NT, 4)
void dsma_kernel(const float* __restrict__ Qp, const float* __restrict__ Kf,
                 const float* __restrict__ Vf,
                 const unsigned short* __restrict__ Kb,
                 const unsigned short* __restrict__ VT,
                 const float* __restrict__ Sp, const float* __restrict__ Gp,
                 float* __restrict__ Op, float* __restrict__ wsout)
{
  __shared__ __align__(16) char smem[65536 + 2048];
  char*  Wlds = smem;                           // region X: K dbuf -> W [32][1024]
  float* red0 = (float*)(smem + 65536);         // [2][8][16] : l1
  float* red1 = (float*)(smem + 65536 + 1024);  // [2][8][16] : l2

  const int tid  = (int)threadIdx.x;
  const int lane = tid & 63;
  const int wid  = tid >> 6;
  const int g4   = lane >> 4;
  const int ll   = lane & 15;
  const int bid  = (int)blockIdx.x;
  const int logical = (bid & 7) * 128 + (bid >> 3);
  const int b     = logical >> 5;
  const int qbase = (logical & 31) * QT;
  const int cb0   = wid * 128;
  const int gid   = bid * NT + tid;

  const float scale = Sp[0];
  const float* Qb = Qp + ((size_t)b * LQ + qbase) * DIM;
  const float* Gb = Gp + ((size_t)b * LQ + qbase) * (size_t)LQ;

  // Q fragments for both q-groups (rows ll and 16+ll), pre-scaled
  bf16x8 qf0[4], qf1[4];
  #pragma unroll
  for (int dc = 0; dc < 4; ++dc) {
    const float* qp0 = Qb + ll * DIM + g4 * 8 + dc * 32;
    const float* qp1 = Qb + (16 + ll) * DIM + g4 * 8 + dc * 32;
    f32x4 a0 = *(const f32x4*)qp0;       f32x4 c0 = *(const f32x4*)(qp0 + 4);
    f32x4 a1 = *(const f32x4*)qp1;       f32x4 c1 = *(const f32x4*)(qp1 + 4);
    a0 *= scale; c0 *= scale; a1 *= scale; c1 *= scale;
    qf0[dc] = pack8(a0, c0);  qf1[dc] = pack8(a1, c1);
  }

  // Phase 1: S^T via mfma(K, Q); each K-tile feeds BOTH q-groups.
  f32x4 S0[8], S1[8];
  #pragma unroll
  for (int s = 0; s < 8; ++s) {
    S0[s][0]=0.f; S0[s][1]=0.f; S0[s][2]=0.f; S0[s][3]=0.f;
    S1[s][0]=0.f; S1[s][1]=0.f; S1[s][2]=0.f; S1[s][3]=0.f;
  }
  if constexpr (PRE) {
    const unsigned short* Kbb = Kb + (size_t)b * LQ * DIM;
    auto kstage = [&](int c) {
      char* base = smem + ((c & 1) * 32768) + wid * 4096;
      #pragma unroll
      for (int i = 0; i < 4; ++i) {
        int j   = i * 4 + (lane >> 4);          // local row 0..15
        int s16 = lane & 15;                    // 16B slot within row
        int gr  = cb0 + c * 16 + j;             // global k-row
        const unsigned short* gp =
            Kbb + (size_t)gr * DIM + ((s16 ^ (j & 7)) * 8);
        __builtin_amdgcn_global_load_lds(
            (const __attribute__((address_space(1))) void*)gp,
            (__attribute__((address_space(3))) void*)(base + i * 1024),
            16, 0, 0);
      }
    };
    kstage(0); kstage(1);
    #pragma unroll
    for (int c = 0; c < 8; ++c) {
      if (c < 6) {
        kstage(c + 2);
        asm volatile("s_waitcnt vmcnt(8)" ::: "memory");
      } else if (c == 6) {
        asm volatile("s_waitcnt vmcnt(4)" ::: "memory");
      } else {
        asm volatile("s_waitcnt vmcnt(0)" ::: "memory");
      }
      __builtin_amdgcn_sched_barrier(0);
      const char* rb = smem + ((c & 1) * 32768) + wid * 4096;
      #pragma unroll
      for (int dc = 0; dc < 4; ++dc) {
        int rbyt = ll * 256 + ((((dc * 4 + g4) * 16)) ^ ((ll & 7) << 4));
        bf16x8 kf = *(const bf16x8*)(rb + rbyt);
        S0[c] = __builtin_amdgcn_mfma_f32_16x16x32_bf16(kf, qf0[dc], S0[c], 0, 0, 0);
        S1[c] = __builtin_amdgcn_mfma_f32_16x16x32_bf16(kf, qf1[dc], S1[c], 0, 0, 0);
      }
    }
  } else {
    const float* Kbf = Kf + (size_t)b * LQ * DIM;
    #pragma unroll
    for (int s = 0; s < 8; ++s) {
      const float* kp = Kbf + (size_t)(cb0 + s * 16 + ll) * DIM + g4 * 8;
      #pragma unroll
      for (int dc = 0; dc < 4; ++dc) {
        f32x4 a = *(const f32x4*)(kp + dc * 32);
        f32x4 c = *(const f32x4*)(kp + dc * 32 + 4);
        bf16x8 kf = pack8(a, c);
        S0[s] = __builtin_amdgcn_mfma_f32_16x16x32_bf16(kf, qf0[dc], S0[s], 0, 0, 0);
        S1[s] = __builtin_amdgcn_mfma_f32_16x16x32_bf16(kf, qf1[dc], S1[s], 0, 0, 0);
      }
    }
  }

  if constexpr (VAR == 3) {   // ---- ablation: phase 1 only
    float o = 0.f;
    #pragma unroll
    for (int s = 0; s < 8; ++s) {
      o += (S0[s][0] + S0[s][1]) + (S0[s][2] + S0[s][3]);
      o += (S1[s][0] + S1[s][1]) + (S1[s][2] + S1[s][3]);
    }
    wsout[2 * 524288 + gid] = o;
    return;
  }

  // G prefetch for group 0 (only needed when phase 3 runs).
  f32x4 gpre[8];
  if constexpr (VAR <= 1) {
    const float* gp = Gb + (size_t)ll * LQ + cb0;
    #pragma unroll
    for (int s = 0; s < 8; ++s)
      gpre[s] = __builtin_nontemporal_load((const f32x4*)(gp + s * 16 + g4 * 4));
  }

  // Phase 2: softmax1 denominators for both groups (no max-sub; ~N(0,1)).
  float lsum0 = 0.f, lsum1 = 0.f;
  #pragma unroll
  for (int s = 0; s < 8; ++s) {
    #pragma unroll
    for (int r = 0; r < 4; ++r) {
      float e0 = __expf(S0[s][r]);  S0[s][r] = e0;  lsum0 += e0;
      float e1 = __expf(S1[s][r]);  S1[s][r] = e1;  lsum1 += e1;
    }
  }
  lsum0 += __shfl_xor(lsum0, 16, 64);  lsum0 += __shfl_xor(lsum0, 32, 64);
  lsum1 += __shfl_xor(lsum1, 16, 64);  lsum1 += __shfl_xor(lsum1, 32, 64);
  if (lane < 16) {
    red0[wid * 16 + lane]       = lsum0;
    red0[128 + wid * 16 + lane] = lsum1;
  }
  __syncthreads();   // also: all waves past phase-1 LDS reads -> W may reuse X
  float l1i0 = 0.f, l1i1 = 0.f;
  #pragma unroll
  for (int w = 0; w < 8; ++w) {
    l1i0 += red0[w * 16 + ll];
    l1i1 += red0[128 + w * 16 + ll];
  }
  l1i0 = 1.0f / l1i0;  l1i1 = 1.0f / l1i1;

  if constexpr (VAR == 2) {   // ---- ablation: phases 1-2
    float o = l1i0 + l1i1;
    #pragma unroll
    for (int s = 0; s < 8; ++s) {
      o += (S0[s][0] + S0[s][1]) + (S0[s][2] + S0[s][3]);
      o += (S1[s][0] + S1[s][1]) + (S1[s][2] + S1[s][3]);
    }
    wsout[1 * 524288 + gid] = o;
    return;
  }

  // Phase 3a: group 0 -> W rows [0,16); gpre[s] is reloaded with group-1 G.
  const float* gp1 = Gb + (size_t)(16 + ll) * LQ + cb0;
  float l2p0 = 0.f, l2p1 = 0.f;
  #pragma unroll
  for (int s = 0; s < 8; ++s) {
    f32x4 g = gpre[s];
    gpre[s] = __builtin_nontemporal_load((const f32x4*)(gp1 + s * 16 + g4 * 4));
    float w0 = __expf(S0[s][0] * l1i0 * g[0]);
    float w1 = __expf(S0[s][1] * l1i0 * g[1]);
    float w2 = __expf(S0[s][2] * l1i0 * g[2]);
    float w3 = __expf(S0[s][3] * l1i0 * g[3]);
    l2p0 += (w0 + w1) + (w2 + w3);
    u32x2 pk; pk[0] = pk2(w0, w1); pk[1] = pk2(w2, w3);
    int byt = ll * 2048 + (cb0 + s * 16 + g4 * 4) * 2;
    byt ^= (ll & 7) << 4;
    *(u32x2*)(Wlds + byt) = pk;
  }
  // Phase 3b: group 1 -> W rows [16,32)
  #pragma unroll
  for (int s = 0; s < 8; ++s) {
    f32x4 g = gpre[s];
    float w0 = __expf(S1[s][0] * l1i1 * g[0]);
    float w1 = __expf(S1[s][1] * l1i1 * g[1]);
    float w2 = __expf(S1[s][2] * l1i1 * g[2]);
    float w3 = __expf(S1[s][3] * l1i1 * g[3]);
    l2p1 += (w0 + w1) + (w2 + w3);
    u32x2 pk; pk[0] = pk2(w0, w1); pk[1] = pk2(w2, w3);
    int byt = (16 + ll) * 2048 + (cb0 + s * 16 + g4 * 4) * 2;
    byt ^= (ll & 7) << 4;   // (16+ll)&7 == ll&7
    *(u32x2*)(Wlds + byt) = pk;
  }
  l2p0 += __shfl_xor(l2p0, 16, 64);  l2p0 += __shfl_xor(l2p0, 32, 64);
  l2p1 += __shfl_xor(l2p1, 16, 64);  l2p1 += __shfl_xor(l2p1, 32, 64);
  if (lane < 16) {
    red1[wid * 16 + lane]       = l2p0;
    red1[128 + wid * 16 + lane] = l2p1;
  }
  __syncthreads();   // W complete + l2 partials complete

  float l2i0[4], l2i1[4];
  #pragma unroll
  for (int r = 0; r < 4; ++r) {
    float t0 = 0.f, t1 = 0.f;
    #pragma unroll
    for (int w = 0; w < 8; ++w) {
      t0 += red1[w * 16 + g4 * 4 + r];
      t1 += red1[128 + w * 16 + g4 * 4 + r];
    }
    l2i0[r] = 1.0f / t0;  l2i1[r] = 1.0f / t1;
  }

  if constexpr (VAR == 1) {   // ---- ablation: phases 1-3 (no PV)
    float o = 0.f;
    #pragma unroll
    for (int r = 0; r < 4; ++r) o += l2i0[r] + l2i1[r];
    // read W back so the LDS stores can't be DCE'd
    int rb = (ll * 2048 + (cb0 + g4 * 4) * 2) ^ ((ll & 7) << 4);
    o += (float)*(short*)(Wlds + rb);
    wsout[0 * 524288 + gid] = o;
    return;
  }

  // Phase 4: O = W V; wave owns d-subtile [wid*16,+16). 4-deep V ring.
  f32x4 acc0 = {0.f, 0.f, 0.f, 0.f}, acc1 = {0.f, 0.f, 0.f, 0.f};
  const int dsub = wid * 16;
  auto wuse2 = [&](bf16x8 vf, int ff) {
    int ab0 = ll * 2048 + (ff * 32 + g4 * 8) * 2;        ab0 ^= (ll & 7) << 4;
    int ab1 = (16 + ll) * 2048 + (ff * 32 + g4 * 8) * 2; ab1 ^= (ll & 7) << 4;
    bf16x8 af0 = *(const bf16x8*)(Wlds + ab0);
    bf16x8 af1 = *(const bf16x8*)(Wlds + ab1);
    acc0 = __builtin_amdgcn_mfma_f32_16x16x32_bf16(af0, vf, acc0, 0, 0, 0);
    acc1 = __builtin_amdgcn_mfma_f32_16x16x32_bf16(af1, vf, acc1, 0, 0, 0);
  };
  if constexpr (PRE) {
    const unsigned short* vrow = VT + (size_t)b * LQ * DIM +
                                 (size_t)(dsub + ll) * LQ;
    auto vld = [&](int f) { return *(const bf16x8*)(vrow + f * 32 + g4 * 8); };
    bf16x8 r0 = vld(0), r1 = vld(1), r2 = vld(2), r3 = vld(3);
    #pragma unroll
    for (int f = 0; f < 32; f += 4) {
      wuse2(r0, f);     if (f + 4 < 32) r0 = vld(f + 4);
      wuse2(r1, f + 1); if (f + 5 < 32) r1 = vld(f + 5);
      wuse2(r2, f + 2); if (f + 6 < 32) r2 = vld(f + 6);
      wuse2(r3, f + 3); if (f + 7 < 32) r3 = vld(f + 7);
    }
  } else {
    const float* vcol = Vf + (size_t)b * LQ * DIM + dsub + ll;
    #pragma unroll
    for (int f = 0; f < 32; ++f) {
      const float* vp = vcol + (size_t)(f * 32 + g4 * 8) * DIM;
      union { unsigned u[4]; bf16x8 v; } vf;
      vf.u[0] = pk2(vp[0 * DIM], vp[1 * DIM]);
      vf.u[1] = pk2(vp[2 * DIM], vp[3 * DIM]);
      vf.u[2] = pk2(vp[4 * DIM], vp[5 * DIM]);
      vf.u[3] = pk2(vp[6 * DIM], vp[7 * DIM]);
      wuse2(vf.v, f);
    }
  }

  // Epilogue: normalize, non-temporal store (write-once stream)
  float* op = Op + ((size_t)b * LQ + qbase) * DIM + dsub + ll;
  #pragma unroll
  for (int r = 0; r < 4; ++r) {
    __builtin_nontemporal_store(acc0[r] * l2i0[r],
                                op + (size_t)(g4 * 4 + r) * DIM);
    __builtin_nontemporal_store(acc1[r] * l2i1[r],
                                op + (size_t)(16 + g4 * 4 + r) * DIM);
  }
}

extern "C" void kernel_launch(void* const* d_in, const int* in_sizes, int n_in,
                              void* d_out, int out_size, void* d_ws, size_t ws_size,
                              hipStream_t stream) {
  const float* Q = (const float*)d_in[0];
  const float* K = (const float*)d_in[1];
  const float* V = (const float*)d_in[2];
  const float* s = (const float*)d_in[3];
  const float* G = (const float*)d_in[4];
  float* O = (float*)d_out;

  const size_t elems = (size_t)32 * LQ * DIM;           // per tensor
  const size_t need  = elems * 2 /*bf16*/ * 2 /*K+VT*/; // 16 MB
  const size_t abl   = (size_t)3 * 524288 * 4;          // 6 MB ablation out
  if (ws_size >= need) {
    unsigned short* Kb = (unsigned short*)d_ws;
    unsigned short* VT = Kb + elems;
    float* wsout = (float*)((char*)d_ws + need);
    prep_kv<<<256, NT, 0, stream>>>(K, V, Kb, VT);
    dsma_kernel<true, 0><<<1024, NT, 0, stream>>>(Q, K, V, Kb, VT, s, G, O, wsout);
    if (ws_size >= need + abl) {   // diagnostic ablation dispatches (ws only)
      dsma_kernel<true, 1><<<1024, NT, 0, stream>>>(Q, K, V, Kb, VT, s, G, O, wsout);
      dsma_kernel<true, 2><<<1024, NT, 0, stream>>>(Q, K, V, Kb, VT, s, G, O, wsout);
      dsma_kernel<true, 3><<<1024, NT, 0, stream>>>(Q, K, V, Kb, VT, s, G, O, wsout);
    }
  } else {
    dsma_kernel<false, 0><<<2048 / 2, NT, 0, stream>>>(Q, K, V, nullptr, nullptr, s, G, O,
                                                       (float*)d_ws);
  }
}

// Round 14
// 94.857 us; speedup vs baseline: 2.0484x; 2.0484x over previous
//
#include <hip/hip_runtime.h>

#define LQ 1024
#define DIM 128
#define NT 512
#define QT 32

typedef __attribute__((ext_vector_type(8))) short bf16x8;
typedef __attribute__((ext_vector_type(4))) float f32x4;
typedef __attribute__((ext_vector_type(2))) unsigned u32x2;

__device__ __forceinline__ unsigned pk2(float a, float b) {
  unsigned short ux = __builtin_bit_cast(unsigned short, (__bf16)a);
  unsigned short uy = __builtin_bit_cast(unsigned short, (__bf16)b);
  return (unsigned)ux | ((unsigned)uy << 16);
}
__device__ __forceinline__ bf16x8 pack8(f32x4 a, f32x4 b) {
  union { unsigned u[4]; bf16x8 v; } r;
  r.u[0] = pk2(a[0], a[1]); r.u[1] = pk2(a[2], a[3]);
  r.u[2] = pk2(b[0], b[1]); r.u[3] = pk2(b[2], b[3]);
  return r.v;
}

// ---------------- prepass: K fp32->bf16 copy; V fp32 -> bf16 transposed [d][k]
__global__ __launch_bounds__(NT)
void prep_kv(const float* __restrict__ Kp, const float* __restrict__ Vp,
             unsigned short* __restrict__ Kb, unsigned short* __restrict__ VT)
{
  __shared__ __align__(16) char lds[32768];
  const int t = (int)threadIdx.x;
  const int bid = (int)blockIdx.x;            // 256 blocks
  const int logical = (bid & 7) * 32 + (bid >> 3);  // XCD-chunked (matches main)
  const int b = logical >> 3;                 // batch
  const int o = logical & 7;                  // k-octant (128 rows)
  const size_t boff = (size_t)b * (LQ * DIM);

  { // K convert-copy rows [o*128, o*128+128)
    const float* src = Kp + boff + (size_t)o * 128 * DIM;
    unsigned short* dst = Kb + boff + (size_t)o * 128 * DIM;
    #pragma unroll
    for (int j = 0; j < 8; ++j) {
      int off = j * 2048 + t * 4;
      f32x4 v = __builtin_nontemporal_load((const f32x4*)(src + off));
      u32x2 p; p[0] = pk2(v[0], v[1]); p[1] = pk2(v[2], v[3]);
      *(u32x2*)(dst + off) = p;
    }
  }
  { // V transpose via swizzled LDS: rows [o*128..+128) -> VT[d][o*128+k]
    const float* src = Vp + boff + (size_t)o * 128 * DIM;
    #pragma unroll
    for (int i = 0; i < 8; ++i) {
      int kr = i * 16 + (t >> 5);
      int d4 = t & 31;
      f32x4 v = __builtin_nontemporal_load(
          (const f32x4*)(src + (size_t)kr * DIM + d4 * 4));
      #pragma unroll
      for (int dd = 0; dd < 4; ++dd) {
        int d = d4 * 4 + dd;
        int byt = (d * 256 + kr * 2) ^ ((d & 7) << 4);
        *(unsigned short*)(lds + byt) =
            __builtin_bit_cast(unsigned short, (__bf16)v[dd]);
      }
    }
    __syncthreads();
    #pragma unroll
    for (int j = 0; j < 4; ++j) {
      int d = j * 32 + (t >> 4);
      int k4 = t & 15;
      int byt = (d * 256 + k4 * 16) ^ ((d & 7) << 4);
      f32x4 x = *(const f32x4*)(lds + byt);
      *(f32x4*)(VT + boff + (size_t)d * LQ + o * 128 + k4 * 8) = x;
    }
  }
}

// ---------------- main kernel: R9 verified structure + phase-4 changes:
// 8-deep V ring (vs 4) with the ring head issued BEFORE the second
// __syncthreads -- loads depend only on VT, the barrier's vmcnt drain
// completes them during natural wave skew, and post-barrier MFMAs start
// immediately. All compiler-visible (no inline-asm vmem): zero ordering risk.
template<bool PRE>
__global__ __launch_bounds__(NT, 4)
void dsma_kernel(const float* __restrict__ Qp, const float* __restrict__ Kf,
                 const float* __restrict__ Vf,
                 const unsigned short* __restrict__ Kb,
                 const unsigned short* __restrict__ VT,
                 const float* __restrict__ Sp, const float* __restrict__ Gp,
                 float* __restrict__ Op)
{
  __shared__ __align__(16) char smem[65536 + 2048];
  char*  Wlds = smem;                           // region X: K dbuf -> W [32][1024]
  float* red0 = (float*)(smem + 65536);         // [2][8][16] : l1
  float* red1 = (float*)(smem + 65536 + 1024);  // [2][8][16] : l2

  const int tid  = (int)threadIdx.x;
  const int lane = tid & 63;
  const int wid  = tid >> 6;
  const int g4   = lane >> 4;
  const int ll   = lane & 15;
  const int bid  = (int)blockIdx.x;
  // XCD-chunked bijective swizzle: 1024 blocks, XCD x owns batches [4x,4x+4)
  const int logical = (bid & 7) * 128 + (bid >> 3);
  const int b     = logical >> 5;
  const int qbase = (logical & 31) * QT;
  const int cb0   = wid * 128;

  const float scale = Sp[0];
  const float* Qb = Qp + ((size_t)b * LQ + qbase) * DIM;
  const float* Gb = Gp + ((size_t)b * LQ + qbase) * (size_t)LQ;

  // Q fragments for both q-groups (rows ll and 16+ll), pre-scaled
  bf16x8 qf0[4], qf1[4];
  #pragma unroll
  for (int dc = 0; dc < 4; ++dc) {
    const float* qp0 = Qb + ll * DIM + g4 * 8 + dc * 32;
    const float* qp1 = Qb + (16 + ll) * DIM + g4 * 8 + dc * 32;
    f32x4 a0 = *(const f32x4*)qp0;       f32x4 c0 = *(const f32x4*)(qp0 + 4);
    f32x4 a1 = *(const f32x4*)qp1;       f32x4 c1 = *(const f32x4*)(qp1 + 4);
    a0 *= scale; c0 *= scale; a1 *= scale; c1 *= scale;
    qf0[dc] = pack8(a0, c0);  qf1[dc] = pack8(a1, c1);
  }

  // Phase 1: S^T via mfma(K, Q); each K-tile feeds BOTH q-groups.
  f32x4 S0[8], S1[8];
  #pragma unroll
  for (int s = 0; s < 8; ++s) {
    S0[s][0]=0.f; S0[s][1]=0.f; S0[s][2]=0.f; S0[s][3]=0.f;
    S1[s][0]=0.f; S1[s][1]=0.f; S1[s][2]=0.f; S1[s][3]=0.f;
  }
  if constexpr (PRE) {
    const unsigned short* Kbb = Kb + (size_t)b * LQ * DIM;
    auto kstage = [&](int c) {
      char* base = smem + ((c & 1) * 32768) + wid * 4096;
      #pragma unroll
      for (int i = 0; i < 4; ++i) {
        int j   = i * 4 + (lane >> 4);          // local row 0..15
        int s16 = lane & 15;                    // 16B slot within row
        int gr  = cb0 + c * 16 + j;             // global k-row
        const unsigned short* gp =
            Kbb + (size_t)gr * DIM + ((s16 ^ (j & 7)) * 8);
        __builtin_amdgcn_global_load_lds(
            (const __attribute__((address_space(1))) void*)gp,
            (__attribute__((address_space(3))) void*)(base + i * 1024),
            16, 0, 0);
      }
    };
    kstage(0); kstage(1);
    #pragma unroll
    for (int c = 0; c < 8; ++c) {
      if (c < 6) {
        kstage(c + 2);
        asm volatile("s_waitcnt vmcnt(8)" ::: "memory");
      } else if (c == 6) {
        asm volatile("s_waitcnt vmcnt(4)" ::: "memory");
      } else {
        asm volatile("s_waitcnt vmcnt(0)" ::: "memory");
      }
      __builtin_amdgcn_sched_barrier(0);
      const char* rb = smem + ((c & 1) * 32768) + wid * 4096;
      #pragma unroll
      for (int dc = 0; dc < 4; ++dc) {
        int rbyt = ll * 256 + ((((dc * 4 + g4) * 16)) ^ ((ll & 7) << 4));
        bf16x8 kf = *(const bf16x8*)(rb + rbyt);
        S0[c] = __builtin_amdgcn_mfma_f32_16x16x32_bf16(kf, qf0[dc], S0[c], 0, 0, 0);
        S1[c] = __builtin_amdgcn_mfma_f32_16x16x32_bf16(kf, qf1[dc], S1[c], 0, 0, 0);
      }
    }
  } else {
    const float* Kbf = Kf + (size_t)b * LQ * DIM;
    #pragma unroll
    for (int s = 0; s < 8; ++s) {
      const float* kp = Kbf + (size_t)(cb0 + s * 16 + ll) * DIM + g4 * 8;
      #pragma unroll
      for (int dc = 0; dc < 4; ++dc) {
        f32x4 a = *(const f32x4*)(kp + dc * 32);
        f32x4 c = *(const f32x4*)(kp + dc * 32 + 4);
        bf16x8 kf = pack8(a, c);
        S0[s] = __builtin_amdgcn_mfma_f32_16x16x32_bf16(kf, qf0[dc], S0[s], 0, 0, 0);
        S1[s] = __builtin_amdgcn_mfma_f32_16x16x32_bf16(kf, qf1[dc], S1[s], 0, 0, 0);
      }
    }
  }

  // G prefetch for group 0 (rows qbase+ll): resolves under phase 2.
  f32x4 gpre[8];
  {
    const float* gp = Gb + (size_t)ll * LQ + cb0;
    #pragma unroll
    for (int s = 0; s < 8; ++s)
      gpre[s] = __builtin_nontemporal_load((const f32x4*)(gp + s * 16 + g4 * 4));
  }

  // Phase 2: softmax1 denominators for both groups (no max-sub; ~N(0,1)).
  float lsum0 = 0.f, lsum1 = 0.f;
  #pragma unroll
  for (int s = 0; s < 8; ++s) {
    #pragma unroll
    for (int r = 0; r < 4; ++r) {
      float e0 = __expf(S0[s][r]);  S0[s][r] = e0;  lsum0 += e0;
      float e1 = __expf(S1[s][r]);  S1[s][r] = e1;  lsum1 += e1;
    }
  }
  lsum0 += __shfl_xor(lsum0, 16, 64);  lsum0 += __shfl_xor(lsum0, 32, 64);
  lsum1 += __shfl_xor(lsum1, 16, 64);  lsum1 += __shfl_xor(lsum1, 32, 64);
  if (lane < 16) {
    red0[wid * 16 + lane]       = lsum0;
    red0[128 + wid * 16 + lane] = lsum1;
  }
  __syncthreads();   // all waves past phase-1 LDS reads -> W may reuse X
  float l1i0 = 0.f, l1i1 = 0.f;
  #pragma unroll
  for (int w = 0; w < 8; ++w) {
    l1i0 += red0[w * 16 + ll];
    l1i1 += red0[128 + w * 16 + ll];
  }
  l1i0 = 1.0f / l1i0;  l1i1 = 1.0f / l1i1;

  // Phase 3a: group 0 -> W rows [0,16); each consumed gpre[s] register is
  // reloaded with the group-1 G value (stagger keeps regs bounded).
  const float* gp1 = Gb + (size_t)(16 + ll) * LQ + cb0;
  float l2p0 = 0.f, l2p1 = 0.f;
  #pragma unroll
  for (int s = 0; s < 8; ++s) {
    f32x4 g = gpre[s];
    gpre[s] = __builtin_nontemporal_load((const f32x4*)(gp1 + s * 16 + g4 * 4));
    float w0 = __expf(S0[s][0] * l1i0 * g[0]);
    float w1 = __expf(S0[s][1] * l1i0 * g[1]);
    float w2 = __expf(S0[s][2] * l1i0 * g[2]);
    float w3 = __expf(S0[s][3] * l1i0 * g[3]);
    l2p0 += (w0 + w1) + (w2 + w3);
    u32x2 pk; pk[0] = pk2(w0, w1); pk[1] = pk2(w2, w3);
    int byt = ll * 2048 + (cb0 + s * 16 + g4 * 4) * 2;
    byt ^= (ll & 7) << 4;
    *(u32x2*)(Wlds + byt) = pk;
  }
  // Phase 3b: group 1 -> W rows [16,32)
  #pragma unroll
  for (int s = 0; s < 8; ++s) {
    f32x4 g = gpre[s];
    float w0 = __expf(S1[s][0] * l1i1 * g[0]);
    float w1 = __expf(S1[s][1] * l1i1 * g[1]);
    float w2 = __expf(S1[s][2] * l1i1 * g[2]);
    float w3 = __expf(S1[s][3] * l1i1 * g[3]);
    l2p1 += (w0 + w1) + (w2 + w3);
    u32x2 pk; pk[0] = pk2(w0, w1); pk[1] = pk2(w2, w3);
    int byt = (16 + ll) * 2048 + (cb0 + s * 16 + g4 * 4) * 2;
    byt ^= (ll & 7) << 4;   // (16+ll)&7 == ll&7
    *(u32x2*)(Wlds + byt) = pk;
  }

  // ---- Phase 4 setup: issue the 8-deep V ring head NOW (before the
  // barrier). Loads depend only on VT; __syncthreads' vmcnt drain completes
  // them during barrier wave-skew; post-barrier MFMAs start immediately.
  const int dsub = wid * 16;
  const unsigned short* vrow = VT + (size_t)b * LQ * DIM +
                               (size_t)(dsub + ll) * LQ;
  auto vld = [&](int f) { return *(const bf16x8*)(vrow + f * 32 + g4 * 8); };
  bf16x8 r0, r1, r2, r3, r4, r5, r6, r7;
  if constexpr (PRE) {
    r0 = vld(0); r1 = vld(1); r2 = vld(2); r3 = vld(3);
    r4 = vld(4); r5 = vld(5); r6 = vld(6); r7 = vld(7);
  }

  l2p0 += __shfl_xor(l2p0, 16, 64);  l2p0 += __shfl_xor(l2p0, 32, 64);
  l2p1 += __shfl_xor(l2p1, 16, 64);  l2p1 += __shfl_xor(l2p1, 32, 64);
  if (lane < 16) {
    red1[wid * 16 + lane]       = l2p0;
    red1[128 + wid * 16 + lane] = l2p1;
  }
  __syncthreads();   // W complete + l2 partials complete (+ V head arrived)

  float l2i0[4], l2i1[4];
  #pragma unroll
  for (int r = 0; r < 4; ++r) {
    float t0 = 0.f, t1 = 0.f;
    #pragma unroll
    for (int w = 0; w < 8; ++w) {
      t0 += red1[w * 16 + g4 * 4 + r];
      t1 += red1[128 + w * 16 + g4 * 4 + r];
    }
    l2i0[r] = 1.0f / t0;  l2i1[r] = 1.0f / t1;
  }

  // Phase 4: O = W V; wave owns d-subtile [wid*16,+16). Each V fragment
  // feeds BOTH q-groups' MFMAs. 8-deep ring (R7-verified pattern).
  f32x4 acc0 = {0.f, 0.f, 0.f, 0.f}, acc1 = {0.f, 0.f, 0.f, 0.f};
  auto wuse2 = [&](bf16x8 vf, int ff) {
    int ab0 = ll * 2048 + (ff * 32 + g4 * 8) * 2;        ab0 ^= (ll & 7) << 4;
    int ab1 = (16 + ll) * 2048 + (ff * 32 + g4 * 8) * 2; ab1 ^= (ll & 7) << 4;
    bf16x8 af0 = *(const bf16x8*)(Wlds + ab0);
    bf16x8 af1 = *(const bf16x8*)(Wlds + ab1);
    acc0 = __builtin_amdgcn_mfma_f32_16x16x32_bf16(af0, vf, acc0, 0, 0, 0);
    acc1 = __builtin_amdgcn_mfma_f32_16x16x32_bf16(af1, vf, acc1, 0, 0, 0);
  };
  if constexpr (PRE) {
    #pragma unroll
    for (int f = 0; f < 32; f += 8) {
      wuse2(r0, f);     if (f + 8  < 32) r0 = vld(f + 8);
      wuse2(r1, f + 1); if (f + 9  < 32) r1 = vld(f + 9);
      wuse2(r2, f + 2); if (f + 10 < 32) r2 = vld(f + 10);
      wuse2(r3, f + 3); if (f + 11 < 32) r3 = vld(f + 11);
      wuse2(r4, f + 4); if (f + 12 < 32) r4 = vld(f + 12);
      wuse2(r5, f + 5); if (f + 13 < 32) r5 = vld(f + 13);
      wuse2(r6, f + 6); if (f + 14 < 32) r6 = vld(f + 14);
      wuse2(r7, f + 7); if (f + 15 < 32) r7 = vld(f + 15);
    }
  } else {
    const float* vcol = Vf + (size_t)b * LQ * DIM + dsub + ll;
    #pragma unroll
    for (int f = 0; f < 32; ++f) {
      const float* vp = vcol + (size_t)(f * 32 + g4 * 8) * DIM;
      union { unsigned u[4]; bf16x8 v; } vf;
      vf.u[0] = pk2(vp[0 * DIM], vp[1 * DIM]);
      vf.u[1] = pk2(vp[2 * DIM], vp[3 * DIM]);
      vf.u[2] = pk2(vp[4 * DIM], vp[5 * DIM]);
      vf.u[3] = pk2(vp[6 * DIM], vp[7 * DIM]);
      wuse2(vf.v, f);
    }
  }

  // Epilogue: normalize, non-temporal store (write-once stream)
  float* op = Op + ((size_t)b * LQ + qbase) * DIM + dsub + ll;
  #pragma unroll
  for (int r = 0; r < 4; ++r) {
    __builtin_nontemporal_store(acc0[r] * l2i0[r],
                                op + (size_t)(g4 * 4 + r) * DIM);
    __builtin_nontemporal_store(acc1[r] * l2i1[r],
                                op + (size_t)(16 + g4 * 4 + r) * DIM);
  }
}

extern "C" void kernel_launch(void* const* d_in, const int* in_sizes, int n_in,
                              void* d_out, int out_size, void* d_ws, size_t ws_size,
                              hipStream_t stream) {
  const float* Q = (const float*)d_in[0];
  const float* K = (const float*)d_in[1];
  const float* V = (const float*)d_in[2];
  const float* s = (const float*)d_in[3];
  const float* G = (const float*)d_in[4];
  float* O = (float*)d_out;

  const size_t elems = (size_t)32 * LQ * DIM;           // per tensor
  const size_t need  = elems * 2 /*bf16*/ * 2 /*K+VT*/; // 16 MB
  if (ws_size >= need) {
    unsigned short* Kb = (unsigned short*)d_ws;
    unsigned short* VT = Kb + elems;
    prep_kv<<<256, NT, 0, stream>>>(K, V, Kb, VT);
    dsma_kernel<true><<<1024, NT, 0, stream>>>(Q, K, V, Kb, VT, s, G, O);
  } else {
    dsma_kernel<false><<<1024, NT, 0, stream>>>(Q, K, V, nullptr, nullptr, s, G, O);
  }
}

// Round 15
// 81.437 us; speedup vs baseline: 2.3860x; 1.1648x over previous
//
#include <hip/hip_runtime.h>

#define LQ 1024
#define DIM 128
#define NT 512
#define QT 64

typedef __attribute__((ext_vector_type(8))) short bf16x8;
typedef __attribute__((ext_vector_type(4))) float f32x4;
typedef __attribute__((ext_vector_type(2))) unsigned u32x2;

__device__ __forceinline__ unsigned pk2(float a, float b) {
  unsigned short ux = __builtin_bit_cast(unsigned short, (__bf16)a);
  unsigned short uy = __builtin_bit_cast(unsigned short, (__bf16)b);
  return (unsigned)ux | ((unsigned)uy << 16);
}
__device__ __forceinline__ bf16x8 pack8(f32x4 a, f32x4 b) {
  union { unsigned u[4]; bf16x8 v; } r;
  r.u[0] = pk2(a[0], a[1]); r.u[1] = pk2(a[2], a[3]);
  r.u[2] = pk2(b[0], b[1]); r.u[3] = pk2(b[2], b[3]);
  return r.v;
}

// ---------------- prepass: K fp32->bf16 copy; V fp32 -> bf16 transposed [d][k]
__global__ __launch_bounds__(NT)
void prep_kv(const float* __restrict__ Kp, const float* __restrict__ Vp,
             unsigned short* __restrict__ Kb, unsigned short* __restrict__ VT)
{
  __shared__ __align__(16) char lds[32768];
  const int t = (int)threadIdx.x;
  const int bid = (int)blockIdx.x;            // 256 blocks
  const int logical = (bid & 7) * 32 + (bid >> 3);
  const int b = logical >> 3;                 // batch
  const int o = logical & 7;                  // k-octant (128 rows)
  const size_t boff = (size_t)b * (LQ * DIM);

  { // K convert-copy rows [o*128, o*128+128)
    const float* src = Kp + boff + (size_t)o * 128 * DIM;
    unsigned short* dst = Kb + boff + (size_t)o * 128 * DIM;
    #pragma unroll
    for (int j = 0; j < 8; ++j) {
      int off = j * 2048 + t * 4;
      f32x4 v = __builtin_nontemporal_load((const f32x4*)(src + off));
      u32x2 p; p[0] = pk2(v[0], v[1]); p[1] = pk2(v[2], v[3]);
      *(u32x2*)(dst + off) = p;
    }
  }
  { // V transpose via swizzled LDS: rows [o*128..+128) -> VT[d][o*128+k]
    const float* src = Vp + boff + (size_t)o * 128 * DIM;
    #pragma unroll
    for (int i = 0; i < 8; ++i) {
      int kr = i * 16 + (t >> 5);
      int d4 = t & 31;
      f32x4 v = __builtin_nontemporal_load(
          (const f32x4*)(src + (size_t)kr * DIM + d4 * 4));
      #pragma unroll
      for (int dd = 0; dd < 4; ++dd) {
        int d = d4 * 4 + dd;
        int byt = (d * 256 + kr * 2) ^ ((d & 7) << 4);
        *(unsigned short*)(lds + byt) =
            __builtin_bit_cast(unsigned short, (__bf16)v[dd]);
      }
    }
    __syncthreads();
    #pragma unroll
    for (int j = 0; j < 4; ++j) {
      int d = j * 32 + (t >> 4);
      int k4 = t & 15;
      int byt = (d * 256 + k4 * 16) ^ ((d & 7) << 4);
      f32x4 x = *(const f32x4*)(lds + byt);
      *(f32x4*)(VT + boff + (size_t)d * LQ + o * 128 + k4 * 8) = x;
    }
  }
}

// ---------------- main kernel: QT=64 -- 4 q-groups share every K/V load.
// K-tile feeds 16 MFMAs (issue-to-use ~2 chunks x 16 MFMA ~ L2 latency:
// staging fully covered); V fragment feeds 4 MFMAs. Per-lane VMEM events
// per unit work drop 1.7x vs QT=32 (the only lever that has worked: R7).
// LDS 132KB -> 1 block/CU; (512,2) -> 256-reg cap, audited peak ~220.
template<bool PRE>
__global__ __launch_bounds__(NT, 2)
void dsma_kernel(const float* __restrict__ Qp, const float* __restrict__ Kf,
                 const float* __restrict__ Vf,
                 const unsigned short* __restrict__ Kb,
                 const unsigned short* __restrict__ VT,
                 const float* __restrict__ Sp, const float* __restrict__ Gp,
                 float* __restrict__ Op)
{
  __shared__ __align__(16) char smem[131072 + 4096];
  char*  Wlds = smem;                           // region X: K dbuf -> W [64][1024]
  float* red0 = (float*)(smem + 131072);        // [4][8][16] : l1
  float* red1 = (float*)(smem + 131072 + 2048); // [4][8][16] : l2

  const int tid  = (int)threadIdx.x;
  const int lane = tid & 63;
  const int wid  = tid >> 6;
  const int g4   = lane >> 4;
  const int ll   = lane & 15;
  const int bid  = (int)blockIdx.x;
  // XCD-chunked bijective swizzle: 512 blocks, XCD x owns batches [4x,4x+4)
  const int logical = (bid & 7) * 64 + (bid >> 3);
  const int b     = logical >> 4;
  const int qbase = (logical & 15) * QT;
  const int cb0   = wid * 128;

  const float scale = Sp[0];
  const float* Qb = Qp + ((size_t)b * LQ + qbase) * DIM;
  const float* Gb = Gp + ((size_t)b * LQ + qbase) * (size_t)LQ;

  // Q fragments for 4 q-groups (rows g*16+ll), pre-scaled
  bf16x8 qf0[4], qf1[4], qf2[4], qf3[4];
  #pragma unroll
  for (int dc = 0; dc < 4; ++dc) {
#define QLOAD(G, DST)                                                        \
    {                                                                        \
      const float* qp = Qb + (G * 16 + ll) * DIM + g4 * 8 + dc * 32;         \
      f32x4 a = *(const f32x4*)qp;  f32x4 c = *(const f32x4*)(qp + 4);       \
      a *= scale; c *= scale;  DST[dc] = pack8(a, c);                        \
    }
    QLOAD(0, qf0) QLOAD(1, qf1) QLOAD(2, qf2) QLOAD(3, qf3)
#undef QLOAD
  }

  // Phase 1: S^T via mfma(K, Q); each K-tile feeds all 4 q-groups.
  // Sg[s][r] = score[k=cb0+s*16+g4*4+r][q=g*16+ll]
  f32x4 S0[8], S1[8], S2[8], S3[8];
  #pragma unroll
  for (int s = 0; s < 8; ++s) {
    S0[s][0]=0.f;S0[s][1]=0.f;S0[s][2]=0.f;S0[s][3]=0.f;
    S1[s][0]=0.f;S1[s][1]=0.f;S1[s][2]=0.f;S1[s][3]=0.f;
    S2[s][0]=0.f;S2[s][1]=0.f;S2[s][2]=0.f;S2[s][3]=0.f;
    S3[s][0]=0.f;S3[s][1]=0.f;S3[s][2]=0.f;S3[s][3]=0.f;
  }
  if constexpr (PRE) {
    const unsigned short* Kbb = Kb + (size_t)b * LQ * DIM;
    auto kstage = [&](int c) {
      char* base = smem + ((c & 1) * 32768) + wid * 4096;
      #pragma unroll
      for (int i = 0; i < 4; ++i) {
        int j   = i * 4 + (lane >> 4);          // local row 0..15
        int s16 = lane & 15;                    // 16B slot within row
        int gr  = cb0 + c * 16 + j;             // global k-row
        const unsigned short* gp =
            Kbb + (size_t)gr * DIM + ((s16 ^ (j & 7)) * 8);
        __builtin_amdgcn_global_load_lds(
            (const __attribute__((address_space(1))) void*)gp,
            (__attribute__((address_space(3))) void*)(base + i * 1024),
            16, 0, 0);
      }
    };
    kstage(0); kstage(1);
    #pragma unroll
    for (int c = 0; c < 8; ++c) {
      if (c < 6) {
        kstage(c + 2);
        asm volatile("s_waitcnt vmcnt(8)" ::: "memory");
      } else if (c == 6) {
        asm volatile("s_waitcnt vmcnt(4)" ::: "memory");
      } else {
        asm volatile("s_waitcnt vmcnt(0)" ::: "memory");
      }
      __builtin_amdgcn_sched_barrier(0);
      const char* rb = smem + ((c & 1) * 32768) + wid * 4096;
      #pragma unroll
      for (int dc = 0; dc < 4; ++dc) {
        int rbyt = ll * 256 + ((((dc * 4 + g4) * 16)) ^ ((ll & 7) << 4));
        bf16x8 kf = *(const bf16x8*)(rb + rbyt);
        S0[c] = __builtin_amdgcn_mfma_f32_16x16x32_bf16(kf, qf0[dc], S0[c], 0, 0, 0);
        S1[c] = __builtin_amdgcn_mfma_f32_16x16x32_bf16(kf, qf1[dc], S1[c], 0, 0, 0);
        S2[c] = __builtin_amdgcn_mfma_f32_16x16x32_bf16(kf, qf2[dc], S2[c], 0, 0, 0);
        S3[c] = __builtin_amdgcn_mfma_f32_16x16x32_bf16(kf, qf3[dc], S3[c], 0, 0, 0);
      }
    }
  } else {
    const float* Kbf = Kf + (size_t)b * LQ * DIM;
    #pragma unroll
    for (int s = 0; s < 8; ++s) {
      const float* kp = Kbf + (size_t)(cb0 + s * 16 + ll) * DIM + g4 * 8;
      #pragma unroll
      for (int dc = 0; dc < 4; ++dc) {
        f32x4 a = *(const f32x4*)(kp + dc * 32);
        f32x4 c = *(const f32x4*)(kp + dc * 32 + 4);
        bf16x8 kf = pack8(a, c);
        S0[s] = __builtin_amdgcn_mfma_f32_16x16x32_bf16(kf, qf0[dc], S0[s], 0, 0, 0);
        S1[s] = __builtin_amdgcn_mfma_f32_16x16x32_bf16(kf, qf1[dc], S1[s], 0, 0, 0);
        S2[s] = __builtin_amdgcn_mfma_f32_16x16x32_bf16(kf, qf2[dc], S2[s], 0, 0, 0);
        S3[s] = __builtin_amdgcn_mfma_f32_16x16x32_bf16(kf, qf3[dc], S3[s], 0, 0, 0);
      }
    }
  }

  // G prefetch for group 0 (row ll): resolves under phase 2's exps.
  f32x4 gpre[8];
  {
    const float* gp = Gb + (size_t)ll * LQ + cb0;
    #pragma unroll
    for (int s = 0; s < 8; ++s)
      gpre[s] = __builtin_nontemporal_load((const f32x4*)(gp + s * 16 + g4 * 4));
  }

  // Phase 2: softmax1 denominators, 4 groups (no max-sub; scores ~N(0,1)).
  float ls0 = 0.f, ls1 = 0.f, ls2 = 0.f, ls3 = 0.f;
  #pragma unroll
  for (int s = 0; s < 8; ++s) {
    #pragma unroll
    for (int r = 0; r < 4; ++r) {
      float e0 = __expf(S0[s][r]); S0[s][r] = e0; ls0 += e0;
      float e1 = __expf(S1[s][r]); S1[s][r] = e1; ls1 += e1;
      float e2 = __expf(S2[s][r]); S2[s][r] = e2; ls2 += e2;
      float e3 = __expf(S3[s][r]); S3[s][r] = e3; ls3 += e3;
    }
  }
  ls0 += __shfl_xor(ls0, 16, 64); ls0 += __shfl_xor(ls0, 32, 64);
  ls1 += __shfl_xor(ls1, 16, 64); ls1 += __shfl_xor(ls1, 32, 64);
  ls2 += __shfl_xor(ls2, 16, 64); ls2 += __shfl_xor(ls2, 32, 64);
  ls3 += __shfl_xor(ls3, 16, 64); ls3 += __shfl_xor(ls3, 32, 64);
  if (lane < 16) {
    red0[0 * 128 + wid * 16 + lane] = ls0;
    red0[1 * 128 + wid * 16 + lane] = ls1;
    red0[2 * 128 + wid * 16 + lane] = ls2;
    red0[3 * 128 + wid * 16 + lane] = ls3;
  }
  __syncthreads();   // all waves past phase-1 LDS reads -> W may reuse X
  float l1i0 = 0.f, l1i1 = 0.f, l1i2 = 0.f, l1i3 = 0.f;
  #pragma unroll
  for (int w = 0; w < 8; ++w) {
    l1i0 += red0[0 * 128 + w * 16 + ll];
    l1i1 += red0[1 * 128 + w * 16 + ll];
    l1i2 += red0[2 * 128 + w * 16 + ll];
    l1i3 += red0[3 * 128 + w * 16 + ll];
  }
  l1i0 = 1.0f / l1i0; l1i1 = 1.0f / l1i1;
  l1i2 = 1.0f / l1i2; l1i3 = 1.0f / l1i3;

  // Phase 3: 4 sub-phases; consumed gpre[s] regs are reloaded with the
  // NEXT group's G row (stagger bounds registers; G latency hides under
  // each sub-phase's 32 exps).
  float l2p0 = 0.f, l2p1 = 0.f, l2p2 = 0.f, l2p3 = 0.f;
#define PH3(Sg, L1I, L2P, ROW, NEXTROW, LOADNEXT)                            \
  {                                                                          \
    const float* gpn = Gb + (size_t)(NEXTROW) * LQ + cb0;                    \
    _Pragma("unroll")                                                        \
    for (int s = 0; s < 8; ++s) {                                            \
      f32x4 g = gpre[s];                                                     \
      if (LOADNEXT)                                                          \
        gpre[s] = __builtin_nontemporal_load(                                \
            (const f32x4*)(gpn + s * 16 + g4 * 4));                          \
      float w0 = __expf(Sg[s][0] * L1I * g[0]);                              \
      float w1 = __expf(Sg[s][1] * L1I * g[1]);                              \
      float w2 = __expf(Sg[s][2] * L1I * g[2]);                              \
      float w3 = __expf(Sg[s][3] * L1I * g[3]);                              \
      L2P += (w0 + w1) + (w2 + w3);                                          \
      u32x2 pk; pk[0] = pk2(w0, w1); pk[1] = pk2(w2, w3);                    \
      int byt = (ROW) * 2048 + (cb0 + s * 16 + g4 * 4) * 2;                  \
      byt ^= (ll & 7) << 4;   /* (g*16+ll)&7 == ll&7 */                      \
      *(u32x2*)(Wlds + byt) = pk;                                            \
    }                                                                        \
  }
  PH3(S0, l1i0, l2p0, ll,      16 + ll, true)
  PH3(S1, l1i1, l2p1, 16 + ll, 32 + ll, true)
  PH3(S2, l1i2, l2p2, 32 + ll, 48 + ll, true)
  PH3(S3, l1i3, l2p3, 48 + ll, ll,      false)
#undef PH3

  // Phase 4 setup: 8-deep V ring head issued BEFORE the barrier (loads
  // depend only on VT; the barrier's drain completes them under wave skew).
  const int dsub = wid * 16;
  const unsigned short* vrow = VT + (size_t)b * LQ * DIM +
                               (size_t)(dsub + ll) * LQ;
  auto vld = [&](int f) { return *(const bf16x8*)(vrow + f * 32 + g4 * 8); };
  bf16x8 r0, r1, r2, r3, r4, r5, r6, r7;
  if constexpr (PRE) {
    r0 = vld(0); r1 = vld(1); r2 = vld(2); r3 = vld(3);
    r4 = vld(4); r5 = vld(5); r6 = vld(6); r7 = vld(7);
  }

  l2p0 += __shfl_xor(l2p0, 16, 64); l2p0 += __shfl_xor(l2p0, 32, 64);
  l2p1 += __shfl_xor(l2p1, 16, 64); l2p1 += __shfl_xor(l2p1, 32, 64);
  l2p2 += __shfl_xor(l2p2, 16, 64); l2p2 += __shfl_xor(l2p2, 32, 64);
  l2p3 += __shfl_xor(l2p3, 16, 64); l2p3 += __shfl_xor(l2p3, 32, 64);
  if (lane < 16) {
    red1[0 * 128 + wid * 16 + lane] = l2p0;
    red1[1 * 128 + wid * 16 + lane] = l2p1;
    red1[2 * 128 + wid * 16 + lane] = l2p2;
    red1[3 * 128 + wid * 16 + lane] = l2p3;
  }
  __syncthreads();   // W complete + l2 partials complete

  float l2i0[4], l2i1[4], l2i2[4], l2i3[4];
  #pragma unroll
  for (int r = 0; r < 4; ++r) {
    float t0 = 0.f, t1 = 0.f, t2 = 0.f, t3 = 0.f;
    #pragma unroll
    for (int w = 0; w < 8; ++w) {
      t0 += red1[0 * 128 + w * 16 + g4 * 4 + r];
      t1 += red1[1 * 128 + w * 16 + g4 * 4 + r];
      t2 += red1[2 * 128 + w * 16 + g4 * 4 + r];
      t3 += red1[3 * 128 + w * 16 + g4 * 4 + r];
    }
    l2i0[r] = 1.0f / t0; l2i1[r] = 1.0f / t1;
    l2i2[r] = 1.0f / t2; l2i3[r] = 1.0f / t3;
  }

  // Phase 4: O = W V; wave owns d-subtile [wid*16,+16). Each V fragment
  // feeds FOUR q-groups' MFMAs. 8-deep ring.
  f32x4 acc0 = {0,0,0,0}, acc1 = {0,0,0,0}, acc2 = {0,0,0,0}, acc3 = {0,0,0,0};
  auto wuse4 = [&](bf16x8 vf, int ff) {
    int kb = (ff * 32 + g4 * 8) * 2;
    int x  = (ll & 7) << 4;
    bf16x8 a0 = *(const bf16x8*)(Wlds + (((ll      ) * 2048 + kb) ^ x));
    bf16x8 a1 = *(const bf16x8*)(Wlds + (((16 + ll ) * 2048 + kb) ^ x));
    bf16x8 a2 = *(const bf16x8*)(Wlds + (((32 + ll ) * 2048 + kb) ^ x));
    bf16x8 a3 = *(const bf16x8*)(Wlds + (((48 + ll ) * 2048 + kb) ^ x));
    acc0 = __builtin_amdgcn_mfma_f32_16x16x32_bf16(a0, vf, acc0, 0, 0, 0);
    acc1 = __builtin_amdgcn_mfma_f32_16x16x32_bf16(a1, vf, acc1, 0, 0, 0);
    acc2 = __builtin_amdgcn_mfma_f32_16x16x32_bf16(a2, vf, acc2, 0, 0, 0);
    acc3 = __builtin_amdgcn_mfma_f32_16x16x32_bf16(a3, vf, acc3, 0, 0, 0);
  };
  if constexpr (PRE) {
    #pragma unroll
    for (int f = 0; f < 32; f += 8) {
      wuse4(r0, f);     if (f + 8  < 32) r0 = vld(f + 8);
      wuse4(r1, f + 1); if (f + 9  < 32) r1 = vld(f + 9);
      wuse4(r2, f + 2); if (f + 10 < 32) r2 = vld(f + 10);
      wuse4(r3, f + 3); if (f + 11 < 32) r3 = vld(f + 11);
      wuse4(r4, f + 4); if (f + 12 < 32) r4 = vld(f + 12);
      wuse4(r5, f + 5); if (f + 13 < 32) r5 = vld(f + 13);
      wuse4(r6, f + 6); if (f + 14 < 32) r6 = vld(f + 14);
      wuse4(r7, f + 7); if (f + 15 < 32) r7 = vld(f + 15);
    }
  } else {
    const float* vcol = Vf + (size_t)b * LQ * DIM + dsub + ll;
    #pragma unroll
    for (int f = 0; f < 32; ++f) {
      const float* vp = vcol + (size_t)(f * 32 + g4 * 8) * DIM;
      union { unsigned u[4]; bf16x8 v; } vf;
      vf.u[0] = pk2(vp[0 * DIM], vp[1 * DIM]);
      vf.u[1] = pk2(vp[2 * DIM], vp[3 * DIM]);
      vf.u[2] = pk2(vp[4 * DIM], vp[5 * DIM]);
      vf.u[3] = pk2(vp[6 * DIM], vp[7 * DIM]);
      wuse4(vf.v, f);
    }
  }

  // Epilogue: normalize, non-temporal store (write-once stream)
  float* op = Op + ((size_t)b * LQ + qbase) * DIM + dsub + ll;
  #pragma unroll
  for (int r = 0; r < 4; ++r) {
    __builtin_nontemporal_store(acc0[r] * l2i0[r],
                                op + (size_t)(g4 * 4 + r) * DIM);
    __builtin_nontemporal_store(acc1[r] * l2i1[r],
                                op + (size_t)(16 + g4 * 4 + r) * DIM);
    __builtin_nontemporal_store(acc2[r] * l2i2[r],
                                op + (size_t)(32 + g4 * 4 + r) * DIM);
    __builtin_nontemporal_store(acc3[r] * l2i3[r],
                                op + (size_t)(48 + g4 * 4 + r) * DIM);
  }
}

extern "C" void kernel_launch(void* const* d_in, const int* in_sizes, int n_in,
                              void* d_out, int out_size, void* d_ws, size_t ws_size,
                              hipStream_t stream) {
  const float* Q = (const float*)d_in[0];
  const float* K = (const float*)d_in[1];
  const float* V = (const float*)d_in[2];
  const float* s = (const float*)d_in[3];
  const float* G = (const float*)d_in[4];
  float* O = (float*)d_out;

  const size_t elems = (size_t)32 * LQ * DIM;           // per tensor
  const size_t need  = elems * 2 /*bf16*/ * 2 /*K+VT*/; // 16 MB
  if (ws_size >= need) {
    unsigned short* Kb = (unsigned short*)d_ws;
    unsigned short* VT = Kb + elems;
    prep_kv<<<256, NT, 0, stream>>>(K, V, Kb, VT);
    dsma_kernel<true><<<512, NT, 0, stream>>>(Q, K, V, Kb, VT, s, G, O);
  } else {
    dsma_kernel<false><<<512, NT, 0, stream>>>(Q, K, V, nullptr, nullptr, s, G, O);
  }
}